// Round 1
// baseline (222.226 us; speedup 1.0000x reference)
//
#include <hip/hip_runtime.h>
#include <hip/hip_bf16.h>

#define HID 768
#define ENTS 9
#define DD 64
#define NOUT 1152     // ENTS*2*DD
#define BATCH 16
#define SEQ 512
#define BIGF 1000000000000.0f
#define ROWLEN (SEQ*SEQ)   // 262144
#define NCHUNK 16
#define CHUNK (ROWLEN/NCHUNK)

typedef __attribute__((ext_vector_type(8))) short short8;
typedef __attribute__((ext_vector_type(4))) float floatx4;
typedef unsigned short ushort_t;

static __device__ __forceinline__ ushort_t f2bf(float x) {
    unsigned int u = __float_as_uint(x);
    unsigned int r = (u + 0x7FFFu + ((u >> 16) & 1u)) >> 16;   // RNE
    return (ushort_t)r;
}

// ---------------- RoPE tables: sin/cos (SEQ x 32) ----------------
__global__ void rope_table_kernel(float* __restrict__ sin_t, float* __restrict__ cos_t) {
    int idx = blockIdx.x * blockDim.x + threadIdx.x;   // 512*32 = 16384
    if (idx >= SEQ * 32) return;
    int m = idx >> 5, i = idx & 31;
    float inv = powf(10000.0f, -2.0f * (float)i / 64.0f);
    float ang = (float)m * inv;
    sin_t[idx] = sinf(ang);
    cos_t[idx] = cosf(ang);
}

// ---------------- f32 -> bf16 convert (X) ----------------
__global__ void cvt_x_kernel(const float* __restrict__ X, ushort_t* __restrict__ Xb, int n) {
    int i = (blockIdx.x * blockDim.x + threadIdx.x) * 4;
    int stride = gridDim.x * blockDim.x * 4;
    for (; i < n; i += stride) {
        float4 f = *(const float4*)&X[i];
        ushort_t u0 = f2bf(f.x), u1 = f2bf(f.y), u2 = f2bf(f.z), u3 = f2bf(f.w);
        ushort_t* p = &Xb[i];
        p[0] = u0; p[1] = u1; p[2] = u2; p[3] = u3;
    }
}

// ---------------- W transpose + convert: Wt[n][k] = bf16(W[k][n]) ----------------
__global__ void cvt_w_kernel(const float* __restrict__ W, ushort_t* __restrict__ Wt) {
    int idx = blockIdx.x * blockDim.x + threadIdx.x;   // over 1152*768
    if (idx >= NOUT * HID) return;
    int n = idx / HID, k = idx - n * HID;
    Wt[idx] = f2bf(W[(size_t)k * NOUT + n]);
}

// ---------------- Projection GEMM + bias + RoPE + pack to q/k bf16 ----------------
// C[m][n], m in [0,8192), n in [0,1152). Tiles 128x128, 4 waves of 64x64.
__global__ __launch_bounds__(256) void proj_rope_kernel(
    const ushort_t* __restrict__ Xb, const ushort_t* __restrict__ Wt,
    const float* __restrict__ bias,
    const float* __restrict__ sin_t, const float* __restrict__ cos_t,
    ushort_t* __restrict__ qbuf, ushort_t* __restrict__ kbuf)
{
    __shared__ ushort_t As[128][40];   // +8 pad: keeps 16B align, ~2-way banks (free)
    __shared__ ushort_t Bs[128][40];
    const int tid  = threadIdx.x;
    const int lane = tid & 63;
    const int wave = tid >> 6;
    const int bm = blockIdx.x * 128;
    const int bn = blockIdx.y * 128;
    const int wm = (wave >> 1) * 64;
    const int wn = (wave & 1) * 64;

    floatx4 acc[4][4];
    #pragma unroll
    for (int i = 0; i < 4; ++i)
        #pragma unroll
        for (int j = 0; j < 4; ++j) { floatx4 z = {0.f,0.f,0.f,0.f}; acc[i][j] = z; }

    const int r  = tid >> 1;
    const int ks = (tid & 1) * 16;
    const int ko = (lane >> 4) * 8;
    const int lr = lane & 15;

    for (int kt = 0; kt < HID; kt += 32) {
        const ushort_t* ga = &Xb[(size_t)(bm + r) * HID + kt + ks];
        const ushort_t* gb = &Wt[(size_t)(bn + r) * HID + kt + ks];
        *(short8*)&As[r][ks]     = *(const short8*)ga;
        *(short8*)&As[r][ks + 8] = *(const short8*)(ga + 8);
        *(short8*)&Bs[r][ks]     = *(const short8*)gb;
        *(short8*)&Bs[r][ks + 8] = *(const short8*)(gb + 8);
        __syncthreads();

        short8 a[4], b[4];
        #pragma unroll
        for (int i = 0; i < 4; ++i) a[i] = *(const short8*)&As[wm + i*16 + lr][ko];
        #pragma unroll
        for (int j = 0; j < 4; ++j) b[j] = *(const short8*)&Bs[wn + j*16 + lr][ko];
        #pragma unroll
        for (int i = 0; i < 4; ++i)
            #pragma unroll
            for (int j = 0; j < 4; ++j)
                acc[i][j] = __builtin_amdgcn_mfma_f32_16x16x32_bf16(a[i], b[j], acc[i][j], 0, 0, 0);
        __syncthreads();
    }

    // epilogue: bias + RoPE (pair partner via shfl_xor lane^1) + pack bf16
    #pragma unroll
    for (int i = 0; i < 4; ++i) {
        #pragma unroll
        for (int j = 0; j < 4; ++j) {
            const int n  = bn + wn + j*16 + lr;
            const int e  = n >> 7;
            const int dd = n & 127;
            const bool isq = dd < DD;
            const int d  = isq ? dd : dd - DD;
            const float sgn = (d & 1) ? 1.0f : -1.0f;
            const float bv = bias[n];
            #pragma unroll
            for (int rg = 0; rg < 4; ++rg) {
                const int m = bm + wm + i*16 + (lane >> 4)*4 + rg;
                const int s = m & (SEQ - 1);
                const int bb = m >> 9;
                float v = acc[i][j][rg] + bv;
                float p = __shfl_xor(v, 1);
                float cc = cos_t[s*32 + (d >> 1)];
                float ss = sin_t[s*32 + (d >> 1)];
                float o = v * cc + sgn * p * ss;
                size_t oidx = (((size_t)(bb * ENTS + e) * SEQ) + s) * DD + d;
                if (isq) qbuf[oidx] = f2bf(o); else kbuf[oidx] = f2bf(o);
            }
        }
    }
}

// ---------------- Batched QK^T + masks + scale -> temp_logits ----------------
__global__ __launch_bounds__(256) void qk_mask_kernel(
    const ushort_t* __restrict__ qbuf, const ushort_t* __restrict__ kbuf,
    const int* __restrict__ amask, float* __restrict__ logits)
{
    __shared__ ushort_t Qs[128][72];
    __shared__ ushort_t Ks[128][72];
    const int tid  = threadIdx.x;
    const int lane = tid & 63;
    const int wave = tid >> 6;
    const int bm = blockIdx.x * 128;
    const int bn = blockIdx.y * 128;
    const int bh = blockIdx.z;           // b*ENTS + h
    const int b  = bh / ENTS;
    const int wm = (wave >> 1) * 64;
    const int wn = (wave & 1) * 64;
    const size_t base = (size_t)bh * SEQ * DD;

    {
        const int r  = tid >> 1;
        const int ks = (tid & 1) * 32;
        const ushort_t* gq = &qbuf[base + (size_t)(bm + r) * DD + ks];
        const ushort_t* gk = &kbuf[base + (size_t)(bn + r) * DD + ks];
        #pragma unroll
        for (int u = 0; u < 4; ++u) {
            *(short8*)&Qs[r][ks + u*8] = *(const short8*)(gq + u*8);
            *(short8*)&Ks[r][ks + u*8] = *(const short8*)(gk + u*8);
        }
    }
    __syncthreads();

    floatx4 acc[4][4];
    #pragma unroll
    for (int i = 0; i < 4; ++i)
        #pragma unroll
        for (int j = 0; j < 4; ++j) { floatx4 z = {0.f,0.f,0.f,0.f}; acc[i][j] = z; }

    const int ko = (lane >> 4) * 8;
    const int lr = lane & 15;
    #pragma unroll
    for (int kk = 0; kk < 2; ++kk) {
        short8 a[4], bf[4];
        #pragma unroll
        for (int i = 0; i < 4; ++i) a[i]  = *(const short8*)&Qs[wm + i*16 + lr][kk*32 + ko];
        #pragma unroll
        for (int j = 0; j < 4; ++j) bf[j] = *(const short8*)&Ks[wn + j*16 + lr][kk*32 + ko];
        #pragma unroll
        for (int i = 0; i < 4; ++i)
            #pragma unroll
            for (int j = 0; j < 4; ++j)
                acc[i][j] = __builtin_amdgcn_mfma_f32_16x16x32_bf16(a[i], bf[j], acc[i][j], 0, 0, 0);
    }

    #pragma unroll
    for (int i = 0; i < 4; ++i) {
        #pragma unroll
        for (int j = 0; j < 4; ++j) {
            const int n = bn + wn + j*16 + lr;
            const float padn = (float)amask[b * SEQ + n];
            #pragma unroll
            for (int rg = 0; rg < 4; ++rg) {
                const int m = bm + wm + i*16 + (lane >> 4)*4 + rg;
                float v = acc[i][j][rg];
                v = v * padn - (1.0f - padn) * BIGF;   // pad mask (ref order)
                if (m > n) v -= BIGF;                  // tril(-1) causal mask
                v *= 0.125f;                           // / sqrt(64)
                logits[((size_t)bh * SEQ + m) * SEQ + n] = v;
            }
        }
    }
}

// ---------------- CE partials: online LSE of y_neg / y_pos per (row, chunk) ----------------
static __device__ __forceinline__ void lse_merge(float& mx, float& sm, float mo, float so) {
    if (mo > mx) { sm = sm * __expf(mx - mo) + so; mx = mo; }
    else         { sm += so * __expf(mo - mx); }
}

__global__ __launch_bounds__(256) void ce_partial_kernel(
    const float* __restrict__ logits, const int* __restrict__ labels,
    float* __restrict__ partials)
{
    const int bid = blockIdx.x;            // row*NCHUNK + chunk, 144*16
    const size_t base = (size_t)bid * CHUNK;
    float mxn = -3.0e38f, smn = 0.f, mxp = -3.0e38f, smp = 0.f;
    for (int idx = threadIdx.x; idx < CHUNK; idx += 256) {
        float t = logits[base + idx];
        int   y = labels[base + idx];
        float vn = y ? (-t - BIGF) : t;        // y_pred - y*BIG
        float vp = y ? (-t)        : (t - BIGF);
        if (vn > mxn) { smn = smn * __expf(mxn - vn) + 1.f; mxn = vn; } else smn += __expf(vn - mxn);
        if (vp > mxp) { smp = smp * __expf(mxp - vp) + 1.f; mxp = vp; } else smp += __expf(vp - mxp);
    }
    #pragma unroll
    for (int off = 32; off > 0; off >>= 1) {
        float mo = __shfl_down(mxn, off), so = __shfl_down(smn, off);
        lse_merge(mxn, smn, mo, so);
        mo = __shfl_down(mxp, off); so = __shfl_down(smp, off);
        lse_merge(mxp, smp, mo, so);
    }
    __shared__ float smx[2][4], ssm[2][4];
    const int lane = threadIdx.x & 63, wv = threadIdx.x >> 6;
    if (lane == 0) { smx[0][wv] = mxn; ssm[0][wv] = smn; smx[1][wv] = mxp; ssm[1][wv] = smp; }
    __syncthreads();
    if (threadIdx.x == 0) {
        float mn = smx[0][0], sn = ssm[0][0], mp = smx[1][0], sp = ssm[1][0];
        #pragma unroll
        for (int u = 1; u < 4; ++u) {
            lse_merge(mn, sn, smx[0][u], ssm[0][u]);
            lse_merge(mp, sp, smx[1][u], ssm[1][u]);
        }
        float4 res = {mn, sn, mp, sp};
        *(float4*)&partials[(size_t)bid * 4] = res;
    }
}

static __device__ __forceinline__ float lae0(float x) {   // logaddexp(0, x)
    return fmaxf(x, 0.f) + log1pf(__expf(-fabsf(x)));
}

__global__ __launch_bounds__(256) void ce_final_kernel(
    const float* __restrict__ partials, float* __restrict__ out)
{
    __shared__ float red[256];
    const int t = threadIdx.x;
    float val = 0.f;
    if (t < BATCH * ENTS) {
        float mn = -3.0e38f, sn = 0.f, mp = -3.0e38f, sp = 0.f;
        for (int c = 0; c < NCHUNK; ++c) {
            const float* p = &partials[(size_t)(t * NCHUNK + c) * 4];
            lse_merge(mn, sn, p[0], p[1]);
            lse_merge(mp, sp, p[2], p[3]);
        }
        float lsen = mn + logf(sn);
        float lsep = mp + logf(sp);
        val = lae0(lsen) + lae0(lsep);
    }
    red[t] = val;
    __syncthreads();
    for (int s2 = 128; s2 > 0; s2 >>= 1) {
        if (t < s2) red[t] += red[t + s2];
        __syncthreads();
    }
    if (t == 0) out[0] = red[0] / (float)(BATCH * ENTS);
}

extern "C" void kernel_launch(void* const* d_in, const int* in_sizes, int n_in,
                              void* d_out, int out_size, void* d_ws, size_t ws_size,
                              hipStream_t stream) {
    const float* X      = (const float*)d_in[0];   // (16,512,768)
    const int*   amask  = (const int*)d_in[1];     // (16,512)
    const int*   labels = (const int*)d_in[2];     // (16,9,512,512)
    const float* W      = (const float*)d_in[3];   // (768,1152)
    const float* bias   = (const float*)d_in[4];   // (1152,)

    float* out    = (float*)d_out;
    float* logits = out + 1;                       // temp_logits (16,9,512,512)

    // workspace layout (~33.4 MB)
    float* sin_t = (float*)d_ws;                         // 16384 f32
    float* cos_t = sin_t + SEQ * 32;                     // 16384 f32
    ushort_t* Xb   = (ushort_t*)(cos_t + SEQ * 32);      // 6291456 bf16
    ushort_t* Wt   = Xb + (size_t)BATCH * SEQ * HID;     // 884736 bf16  [n][k]
    ushort_t* qbuf = Wt + (size_t)NOUT * HID;            // 16*9*512*64 bf16
    ushort_t* kbuf = qbuf + (size_t)BATCH * ENTS * SEQ * DD;
    float* partials = (float*)(kbuf + (size_t)BATCH * ENTS * SEQ * DD); // 144*16*4 f32

    rope_table_kernel<<<64, 256, 0, stream>>>(sin_t, cos_t);
    cvt_x_kernel<<<1024, 256, 0, stream>>>(X, Xb, BATCH * SEQ * HID);
    cvt_w_kernel<<<(NOUT * HID + 255) / 256, 256, 0, stream>>>(W, Wt);
    proj_rope_kernel<<<dim3(64, 9), 256, 0, stream>>>(Xb, Wt, bias, sin_t, cos_t, qbuf, kbuf);
    qk_mask_kernel<<<dim3(4, 4, 144), 256, 0, stream>>>(qbuf, kbuf, amask, logits);
    ce_partial_kernel<<<BATCH * ENTS * NCHUNK, 256, 0, stream>>>(logits, labels, partials);
    ce_final_kernel<<<1, 256, 0, stream>>>(partials, out);
}

// Round 2
// 214.772 us; speedup vs baseline: 1.0347x; 1.0347x over previous
//
#include <hip/hip_runtime.h>
#include <hip/hip_bf16.h>

#define HID 768
#define ENTS 9
#define DD 64
#define NOUT 1152     // ENTS*2*DD
#define BATCH 16
#define SEQ 512
#define BIGF 1000000000000.0f
#define NCHUNK 16

typedef __attribute__((ext_vector_type(8))) short short8;
typedef __attribute__((ext_vector_type(4))) float floatx4;
typedef unsigned short ushort_t;

static __device__ __forceinline__ ushort_t f2bf(float x) {
    unsigned int u = __float_as_uint(x);
    unsigned int r = (u + 0x7FFFu + ((u >> 16) & 1u)) >> 16;   // RNE
    return (ushort_t)r;
}

// ---------------- RoPE tables: sin/cos (SEQ x 32) ----------------
__global__ void rope_table_kernel(float* __restrict__ sin_t, float* __restrict__ cos_t) {
    int idx = blockIdx.x * blockDim.x + threadIdx.x;   // 512*32 = 16384
    if (idx >= SEQ * 32) return;
    int m = idx >> 5, i = idx & 31;
    float inv = powf(10000.0f, -2.0f * (float)i / 64.0f);
    float ang = (float)m * inv;
    sin_t[idx] = sinf(ang);
    cos_t[idx] = cosf(ang);
}

// ---------------- f32 -> bf16 convert (X) ----------------
__global__ void cvt_x_kernel(const float* __restrict__ X, ushort_t* __restrict__ Xb, int n) {
    int i = (blockIdx.x * blockDim.x + threadIdx.x) * 4;
    int stride = gridDim.x * blockDim.x * 4;
    for (; i < n; i += stride) {
        float4 f = *(const float4*)&X[i];
        ushort_t u0 = f2bf(f.x), u1 = f2bf(f.y), u2 = f2bf(f.z), u3 = f2bf(f.w);
        ushort_t* p = &Xb[i];
        p[0] = u0; p[1] = u1; p[2] = u2; p[3] = u3;
    }
}

// ---------------- W transpose + convert: Wt[n][k] = bf16(W[k][n]) ----------------
__global__ void cvt_w_kernel(const float* __restrict__ W, ushort_t* __restrict__ Wt) {
    int idx = blockIdx.x * blockDim.x + threadIdx.x;   // over 1152*768
    if (idx >= NOUT * HID) return;
    int n = idx / HID, k = idx - n * HID;
    Wt[idx] = f2bf(W[(size_t)k * NOUT + n]);
}

// ---------------- Projection GEMM + bias + RoPE + pack to q/k bf16 ----------------
__global__ __launch_bounds__(256) void proj_rope_kernel(
    const ushort_t* __restrict__ Xb, const ushort_t* __restrict__ Wt,
    const float* __restrict__ bias,
    const float* __restrict__ sin_t, const float* __restrict__ cos_t,
    ushort_t* __restrict__ qbuf, ushort_t* __restrict__ kbuf)
{
    __shared__ ushort_t As[128][40];
    __shared__ ushort_t Bs[128][40];
    const int tid  = threadIdx.x;
    const int lane = tid & 63;
    const int wave = tid >> 6;
    const int bm = blockIdx.x * 128;
    const int bn = blockIdx.y * 128;
    const int wm = (wave >> 1) * 64;
    const int wn = (wave & 1) * 64;

    floatx4 acc[4][4];
    #pragma unroll
    for (int i = 0; i < 4; ++i)
        #pragma unroll
        for (int j = 0; j < 4; ++j) { floatx4 z = {0.f,0.f,0.f,0.f}; acc[i][j] = z; }

    const int r  = tid >> 1;
    const int ks = (tid & 1) * 16;
    const int ko = (lane >> 4) * 8;
    const int lr = lane & 15;

    for (int kt = 0; kt < HID; kt += 32) {
        const ushort_t* ga = &Xb[(size_t)(bm + r) * HID + kt + ks];
        const ushort_t* gb = &Wt[(size_t)(bn + r) * HID + kt + ks];
        *(short8*)&As[r][ks]     = *(const short8*)ga;
        *(short8*)&As[r][ks + 8] = *(const short8*)(ga + 8);
        *(short8*)&Bs[r][ks]     = *(const short8*)gb;
        *(short8*)&Bs[r][ks + 8] = *(const short8*)(gb + 8);
        __syncthreads();

        short8 a[4], b[4];
        #pragma unroll
        for (int i = 0; i < 4; ++i) a[i] = *(const short8*)&As[wm + i*16 + lr][ko];
        #pragma unroll
        for (int j = 0; j < 4; ++j) b[j] = *(const short8*)&Bs[wn + j*16 + lr][ko];
        #pragma unroll
        for (int i = 0; i < 4; ++i)
            #pragma unroll
            for (int j = 0; j < 4; ++j)
                acc[i][j] = __builtin_amdgcn_mfma_f32_16x16x32_bf16(a[i], b[j], acc[i][j], 0, 0, 0);
        __syncthreads();
    }

    #pragma unroll
    for (int i = 0; i < 4; ++i) {
        #pragma unroll
        for (int j = 0; j < 4; ++j) {
            const int n  = bn + wn + j*16 + lr;
            const int e  = n >> 7;
            const int dd = n & 127;
            const bool isq = dd < DD;
            const int d  = isq ? dd : dd - DD;
            const float sgn = (d & 1) ? 1.0f : -1.0f;
            const float bv = bias[n];
            #pragma unroll
            for (int rg = 0; rg < 4; ++rg) {
                const int m = bm + wm + i*16 + (lane >> 4)*4 + rg;
                const int s = m & (SEQ - 1);
                const int bb = m >> 9;
                float v = acc[i][j][rg] + bv;
                float p = __shfl_xor(v, 1);
                float cc = cos_t[s*32 + (d >> 1)];
                float ss = sin_t[s*32 + (d >> 1)];
                float o = v * cc + sgn * p * ss;
                size_t oidx = (((size_t)(bb * ENTS + e) * SEQ) + s) * DD + d;
                if (isq) qbuf[oidx] = f2bf(o); else kbuf[oidx] = f2bf(o);
            }
        }
    }
}

// ---------------- lse merge helper ----------------
static __device__ __forceinline__ void lse_merge(float& mx, float& sm, float mo, float so) {
    if (mo > mx) { sm = sm * __expf(mx - mo) + so; mx = mo; }
    else         { sm += so * __expf(mo - mx); }
}

// ---------------- Batched QK^T + masks + scale -> temp_logits, FUSED CE partials ----------------
__global__ __launch_bounds__(256) void qk_mask_ce_kernel(
    const ushort_t* __restrict__ qbuf, const ushort_t* __restrict__ kbuf,
    const int* __restrict__ amask, const int* __restrict__ labels,
    float* __restrict__ logits, float* __restrict__ partials)
{
    __shared__ ushort_t Qs[128][72];
    __shared__ ushort_t Ks[128][72];
    __shared__ float smx[2][4], ssm[2][4];
    const int tid  = threadIdx.x;
    const int lane = tid & 63;
    const int wave = tid >> 6;
    const int bm = blockIdx.x * 128;
    const int bn = blockIdx.y * 128;
    const int bh = blockIdx.z;           // b*ENTS + h
    const int b  = bh / ENTS;
    const int wm = (wave >> 1) * 64;
    const int wn = (wave & 1) * 64;
    const size_t base = (size_t)bh * SEQ * DD;

    {
        const int r  = tid >> 1;
        const int ks = (tid & 1) * 32;
        const ushort_t* gq = &qbuf[base + (size_t)(bm + r) * DD + ks];
        const ushort_t* gk = &kbuf[base + (size_t)(bn + r) * DD + ks];
        #pragma unroll
        for (int u = 0; u < 4; ++u) {
            *(short8*)&Qs[r][ks + u*8] = *(const short8*)(gq + u*8);
            *(short8*)&Ks[r][ks + u*8] = *(const short8*)(gk + u*8);
        }
    }
    __syncthreads();

    floatx4 acc[4][4];
    #pragma unroll
    for (int i = 0; i < 4; ++i)
        #pragma unroll
        for (int j = 0; j < 4; ++j) { floatx4 z = {0.f,0.f,0.f,0.f}; acc[i][j] = z; }

    const int ko = (lane >> 4) * 8;
    const int lr = lane & 15;
    #pragma unroll
    for (int kk = 0; kk < 2; ++kk) {
        short8 a[4], bf[4];
        #pragma unroll
        for (int i = 0; i < 4; ++i) a[i]  = *(const short8*)&Qs[wm + i*16 + lr][kk*32 + ko];
        #pragma unroll
        for (int j = 0; j < 4; ++j) bf[j] = *(const short8*)&Ks[wn + j*16 + lr][kk*32 + ko];
        #pragma unroll
        for (int i = 0; i < 4; ++i)
            #pragma unroll
            for (int j = 0; j < 4; ++j)
                acc[i][j] = __builtin_amdgcn_mfma_f32_16x16x32_bf16(a[i], bf[j], acc[i][j], 0, 0, 0);
    }

    // ---- epilogue pass A: mask+scale, write logits, collect labels, track maxes ----
    unsigned long long ybits = 0ull;
    float mxn = -3.0e38f, mxp = -3.0e38f;
    int cnt = 0;
    #pragma unroll
    for (int i = 0; i < 4; ++i) {
        #pragma unroll
        for (int j = 0; j < 4; ++j) {
            const int n = bn + wn + j*16 + lr;
            const float padn = (float)amask[b * SEQ + n];
            #pragma unroll
            for (int rg = 0; rg < 4; ++rg) {
                const int m = bm + wm + i*16 + (lane >> 4)*4 + rg;
                float v = acc[i][j][rg];
                v = v * padn - (1.0f - padn) * BIGF;   // pad mask (ref order)
                if (m > n) v -= BIGF;                  // tril(-1) causal mask
                v *= 0.125f;                           // / sqrt(64)
                const size_t lidx = ((size_t)bh * SEQ + m) * SEQ + n;
                logits[lidx] = v;
                const int y = labels[lidx];
                ybits |= ((unsigned long long)(y & 1)) << cnt;
                float vn = y ? (-v - BIGF) : v;        // (1-2y)*v - y*BIG
                float vp = y ? (-v)        : (v - BIGF);
                mxn = fmaxf(mxn, vn);
                mxp = fmaxf(mxp, vp);
                acc[i][j][rg] = v;                     // keep masked value for pass B
                ++cnt;
            }
        }
    }

    // ---- pass B: sums of exp(v - max), independent expfs ----
    float smn = 0.f, smp = 0.f;
    cnt = 0;
    #pragma unroll
    for (int i = 0; i < 4; ++i) {
        #pragma unroll
        for (int j = 0; j < 4; ++j) {
            #pragma unroll
            for (int rg = 0; rg < 4; ++rg) {
                const float v = acc[i][j][rg];
                const int y = (int)((ybits >> cnt) & 1ull);
                float vn = y ? (-v - BIGF) : v;
                float vp = y ? (-v)        : (v - BIGF);
                smn += __expf(vn - mxn);
                smp += __expf(vp - mxp);
                ++cnt;
            }
        }
    }

    // ---- wave reduce (64 lanes) ----
    #pragma unroll
    for (int off = 32; off > 0; off >>= 1) {
        float mo = __shfl_down(mxn, off), so = __shfl_down(smn, off);
        lse_merge(mxn, smn, mo, so);
        mo = __shfl_down(mxp, off); so = __shfl_down(smp, off);
        lse_merge(mxp, smp, mo, so);
    }
    if (lane == 0) { smx[0][wave] = mxn; ssm[0][wave] = smn; smx[1][wave] = mxp; ssm[1][wave] = smp; }
    __syncthreads();
    if (tid == 0) {
        float mn = smx[0][0], sn = ssm[0][0], mp = smx[1][0], sp = ssm[1][0];
        #pragma unroll
        for (int u = 1; u < 4; ++u) {
            lse_merge(mn, sn, smx[0][u], ssm[0][u]);
            lse_merge(mp, sp, smx[1][u], ssm[1][u]);
        }
        const int chunk = blockIdx.x * 4 + blockIdx.y;      // 0..15
        float4 res = {mn, sn, mp, sp};
        *(float4*)&partials[(size_t)(bh * NCHUNK + chunk) * 4] = res;
    }
}

static __device__ __forceinline__ float lae0(float x) {   // logaddexp(0, x)
    return fmaxf(x, 0.f) + log1pf(__expf(-fabsf(x)));
}

__global__ __launch_bounds__(256) void ce_final_kernel(
    const float* __restrict__ partials, float* __restrict__ out)
{
    __shared__ float red[256];
    const int t = threadIdx.x;
    float val = 0.f;
    if (t < BATCH * ENTS) {
        float mn = -3.0e38f, sn = 0.f, mp = -3.0e38f, sp = 0.f;
        for (int c = 0; c < NCHUNK; ++c) {
            const float* p = &partials[(size_t)(t * NCHUNK + c) * 4];
            lse_merge(mn, sn, p[0], p[1]);
            lse_merge(mp, sp, p[2], p[3]);
        }
        float lsen = mn + logf(sn);
        float lsep = mp + logf(sp);
        val = lae0(lsen) + lae0(lsep);
    }
    red[t] = val;
    __syncthreads();
    for (int s2 = 128; s2 > 0; s2 >>= 1) {
        if (t < s2) red[t] += red[t + s2];
        __syncthreads();
    }
    if (t == 0) out[0] = red[0] / (float)(BATCH * ENTS);
}

extern "C" void kernel_launch(void* const* d_in, const int* in_sizes, int n_in,
                              void* d_out, int out_size, void* d_ws, size_t ws_size,
                              hipStream_t stream) {
    const float* X      = (const float*)d_in[0];   // (16,512,768)
    const int*   amask  = (const int*)d_in[1];     // (16,512)
    const int*   labels = (const int*)d_in[2];     // (16,9,512,512)
    const float* W      = (const float*)d_in[3];   // (768,1152)
    const float* bias   = (const float*)d_in[4];   // (1152,)

    float* out    = (float*)d_out;
    float* logits = out + 1;                       // temp_logits (16,9,512,512)

    float* sin_t = (float*)d_ws;                         // 16384 f32
    float* cos_t = sin_t + SEQ * 32;                     // 16384 f32
    ushort_t* Xb   = (ushort_t*)(cos_t + SEQ * 32);      // 6291456 bf16
    ushort_t* Wt   = Xb + (size_t)BATCH * SEQ * HID;     // 884736 bf16  [n][k]
    ushort_t* qbuf = Wt + (size_t)NOUT * HID;            // 16*9*512*64 bf16
    ushort_t* kbuf = qbuf + (size_t)BATCH * ENTS * SEQ * DD;
    float* partials = (float*)(kbuf + (size_t)BATCH * ENTS * SEQ * DD); // 144*16*4 f32

    rope_table_kernel<<<64, 256, 0, stream>>>(sin_t, cos_t);
    cvt_x_kernel<<<1024, 256, 0, stream>>>(X, Xb, BATCH * SEQ * HID);
    cvt_w_kernel<<<(NOUT * HID + 255) / 256, 256, 0, stream>>>(W, Wt);
    proj_rope_kernel<<<dim3(64, 9), 256, 0, stream>>>(Xb, Wt, bias, sin_t, cos_t, qbuf, kbuf);
    qk_mask_ce_kernel<<<dim3(4, 4, 144), 256, 0, stream>>>(qbuf, kbuf, amask, labels, logits, partials);
    ce_final_kernel<<<1, 256, 0, stream>>>(partials, out);
}

// Round 3
// 193.655 us; speedup vs baseline: 1.1475x; 1.1090x over previous
//
#include <hip/hip_runtime.h>
#include <hip/hip_bf16.h>

#define HID 768
#define ENTS 9
#define DD 64
#define NOUT 1152     // ENTS*2*DD
#define BATCH 16
#define SEQ 512
#define BIGF 1000000000000.0f
#define NCHUNK 16

typedef __attribute__((ext_vector_type(8))) short short8;
typedef __attribute__((ext_vector_type(4))) short short4_t;
typedef __attribute__((ext_vector_type(4))) float floatx4;
typedef __attribute__((ext_vector_type(4))) int intx4;
typedef unsigned short ushort_t;

static __device__ __forceinline__ ushort_t f2bf(float x) {
    unsigned int u = __float_as_uint(x);
    unsigned int r = (u + 0x7FFFu + ((u >> 16) & 1u)) >> 16;   // RNE
    return (ushort_t)r;
}

static __device__ __forceinline__ void gload16(const void* g, void* l) {
    __builtin_amdgcn_global_load_lds(
        (const __attribute__((address_space(1))) void*)g,
        (__attribute__((address_space(3))) void*)l, 16, 0, 0);
}

// ---------------- RoPE tables: sin/cos (SEQ x 32) ----------------
__global__ void rope_table_kernel(float* __restrict__ sin_t, float* __restrict__ cos_t) {
    int idx = blockIdx.x * blockDim.x + threadIdx.x;   // 512*32 = 16384
    if (idx >= SEQ * 32) return;
    int m = idx >> 5, i = idx & 31;
    float inv = powf(10000.0f, -2.0f * (float)i / 64.0f);
    float ang = (float)m * inv;
    sin_t[idx] = sinf(ang);
    cos_t[idx] = cosf(ang);
}

// ---------------- f32 -> bf16 convert (X) ----------------
__global__ void cvt_x_kernel(const float* __restrict__ X, ushort_t* __restrict__ Xb, int n) {
    int i = (blockIdx.x * blockDim.x + threadIdx.x) * 4;
    int stride = gridDim.x * blockDim.x * 4;
    for (; i < n; i += stride) {
        float4 f = *(const float4*)&X[i];
        ushort_t u0 = f2bf(f.x), u1 = f2bf(f.y), u2 = f2bf(f.z), u3 = f2bf(f.w);
        ushort_t* p = &Xb[i];
        p[0] = u0; p[1] = u1; p[2] = u2; p[3] = u3;
    }
}

// ---------------- W transpose + convert: Wt[n][k] = bf16(W[k][n]) ----------------
__global__ void cvt_w_kernel(const float* __restrict__ W, ushort_t* __restrict__ Wt) {
    int idx = blockIdx.x * blockDim.x + threadIdx.x;   // over 1152*768
    if (idx >= NOUT * HID) return;
    int n = idx / HID, k = idx - n * HID;
    Wt[idx] = f2bf(W[(size_t)k * NOUT + n]);
}

// ---------------- Projection GEMM + bias + RoPE + pack to q/k bf16 ----------------
// Swapped MFMA: acc[j][i] = Wt_tile · Xb_tile^T, so D[n][m]:
//   n = bn + wn + j*16 + (lane>>4)*4 + rg   (4 consecutive per lane)
//   m = bm + wm + i*16 + (lane&15)
// RoPE pairs (2t,2t+1) are in-lane; q/k stores are short4.
__global__ __launch_bounds__(256) void proj_rope_kernel(
    const ushort_t* __restrict__ Xb, const ushort_t* __restrict__ Wt,
    const float* __restrict__ bias,
    const float* __restrict__ sin_t, const float* __restrict__ cos_t,
    ushort_t* __restrict__ qbuf, ushort_t* __restrict__ kbuf)
{
    __shared__ ushort_t As[128 * 32];   // linear: global_load_lds dest
    __shared__ ushort_t Bs[128 * 32];
    const int tid  = threadIdx.x;
    const int lane = tid & 63;
    const int wave = tid >> 6;
    const int bm = blockIdx.x * 128;
    const int bn = blockIdx.y * 128;
    const int wm = (wave >> 1) * 64;
    const int wn = (wave & 1) * 64;

    floatx4 acc[4][4];
    #pragma unroll
    for (int j = 0; j < 4; ++j)
        #pragma unroll
        for (int i = 0; i < 4; ++i) { floatx4 z = {0.f,0.f,0.f,0.f}; acc[j][i] = z; }

    // staging: 512 chunks of 16B per 8KB tile; chunk c = u*256 + wave*64 + lane
    const int c0 = wave * 64 + lane;
    const int c1 = 256 + wave * 64 + lane;
    const int r0 = c0 >> 2, q0 = (c0 & 3) * 8;
    const int r1 = c1 >> 2, q1 = (c1 & 3) * 8;
    ushort_t* ldsA0 = As + wave * 512;          // bytes: wave*1024
    ushort_t* ldsA1 = As + 2048 + wave * 512;   // + 4096B
    ushort_t* ldsB0 = Bs + wave * 512;
    ushort_t* ldsB1 = Bs + 2048 + wave * 512;

    const int ko = (lane >> 4) * 8;
    const int lr = lane & 15;

    for (int kt = 0; kt < HID; kt += 32) {
        gload16(&Xb[(size_t)(bm + r0) * HID + kt + q0], ldsA0);
        gload16(&Xb[(size_t)(bm + r1) * HID + kt + q1], ldsA1);
        gload16(&Wt[(size_t)(bn + r0) * HID + kt + q0], ldsB0);
        gload16(&Wt[(size_t)(bn + r1) * HID + kt + q1], ldsB1);
        __syncthreads();   // drains vmcnt(0)

        short8 a[4], b[4];
        #pragma unroll
        for (int i = 0; i < 4; ++i) a[i] = *(const short8*)&As[(wm + i*16 + lr) * 32 + ko];
        #pragma unroll
        for (int j = 0; j < 4; ++j) b[j] = *(const short8*)&Bs[(wn + j*16 + lr) * 32 + ko];
        #pragma unroll
        for (int j = 0; j < 4; ++j)
            #pragma unroll
            for (int i = 0; i < 4; ++i)
                acc[j][i] = __builtin_amdgcn_mfma_f32_16x16x32_bf16(b[j], a[i], acc[j][i], 0, 0, 0);
        __syncthreads();
    }

    // epilogue: bias + in-lane RoPE + short4 store
    #pragma unroll
    for (int j = 0; j < 4; ++j) {
        const int n0 = bn + wn + j*16 + (lane >> 4) * 4;   // 4 consecutive n
        const int e   = n0 >> 7;
        const int dd0 = n0 & 127;
        const bool isq = dd0 < DD;
        const int d0  = isq ? dd0 : dd0 - DD;              // multiple of 4
        const float4 bv = *(const float4*)&bias[n0];
        #pragma unroll
        for (int i = 0; i < 4; ++i) {
            const int m = bm + wm + i*16 + lr;
            const int s  = m & (SEQ - 1);
            const int bb = m >> 9;
            const float c0 = cos_t[s*32 + (d0 >> 1)];
            const float s0 = sin_t[s*32 + (d0 >> 1)];
            const float c1 = cos_t[s*32 + (d0 >> 1) + 1];
            const float s1 = sin_t[s*32 + (d0 >> 1) + 1];
            const float v0 = acc[j][i][0] + bv.x;
            const float v1 = acc[j][i][1] + bv.y;
            const float v2 = acc[j][i][2] + bv.z;
            const float v3 = acc[j][i][3] + bv.w;
            const float o0 = v0 * c0 - v1 * s0;
            const float o1 = v1 * c0 + v0 * s0;
            const float o2 = v2 * c1 - v3 * s1;
            const float o3 = v3 * c1 + v2 * s1;
            short4_t sv = { (short)f2bf(o0), (short)f2bf(o1), (short)f2bf(o2), (short)f2bf(o3) };
            size_t oidx = (((size_t)(bb * ENTS + e) * SEQ) + s) * DD + d0;
            *(short4_t*)&(isq ? qbuf : kbuf)[oidx] = sv;
        }
    }
}

// ---------------- lse merge helper ----------------
static __device__ __forceinline__ void lse_merge(float& mx, float& sm, float mo, float so) {
    if (mo > mx) { sm = sm * __expf(mx - mo) + so; mx = mo; }
    else         { sm += so * __expf(mo - mx); }
}

// ---------------- Batched QK^T + masks + scale -> temp_logits, FUSED CE partials ----------------
// Swapped MFMA: acc[j][i] = K_tile · Q_tile^T, D[n][m]:
//   n = bn + wn + j*16 + (lane>>4)*4 + rg   -> int4 label loads, float4 logit stores
//   m = bm + wm + i*16 + (lane&15)
__global__ __launch_bounds__(256) void qk_mask_ce_kernel(
    const ushort_t* __restrict__ qbuf, const ushort_t* __restrict__ kbuf,
    const int* __restrict__ amask, const int* __restrict__ labels,
    float* __restrict__ logits, float* __restrict__ partials)
{
    __shared__ ushort_t Qs[128][72];
    __shared__ ushort_t Ks[128][72];
    __shared__ float smx[2][4], ssm[2][4];
    const int tid  = threadIdx.x;
    const int lane = tid & 63;
    const int wave = tid >> 6;
    const int bm = blockIdx.x * 128;
    const int bn = blockIdx.y * 128;
    const int bh = blockIdx.z;           // b*ENTS + h
    const int b  = bh / ENTS;
    const int wm = (wave >> 1) * 64;
    const int wn = (wave & 1) * 64;
    const size_t base = (size_t)bh * SEQ * DD;

    {
        const int r  = tid >> 1;
        const int ks = (tid & 1) * 32;
        const ushort_t* gq = &qbuf[base + (size_t)(bm + r) * DD + ks];
        const ushort_t* gk = &kbuf[base + (size_t)(bn + r) * DD + ks];
        #pragma unroll
        for (int u = 0; u < 4; ++u) {
            *(short8*)&Qs[r][ks + u*8] = *(const short8*)(gq + u*8);
            *(short8*)&Ks[r][ks + u*8] = *(const short8*)(gk + u*8);
        }
    }
    __syncthreads();

    floatx4 acc[4][4];
    #pragma unroll
    for (int j = 0; j < 4; ++j)
        #pragma unroll
        for (int i = 0; i < 4; ++i) { floatx4 z = {0.f,0.f,0.f,0.f}; acc[j][i] = z; }

    const int ko = (lane >> 4) * 8;
    const int lr = lane & 15;
    #pragma unroll
    for (int kk = 0; kk < 2; ++kk) {
        short8 a[4], bf[4];
        #pragma unroll
        for (int i = 0; i < 4; ++i) a[i]  = *(const short8*)&Qs[wm + i*16 + lr][kk*32 + ko];
        #pragma unroll
        for (int j = 0; j < 4; ++j) bf[j] = *(const short8*)&Ks[wn + j*16 + lr][kk*32 + ko];
        #pragma unroll
        for (int j = 0; j < 4; ++j)
            #pragma unroll
            for (int i = 0; i < 4; ++i)
                acc[j][i] = __builtin_amdgcn_mfma_f32_16x16x32_bf16(bf[j], a[i], acc[j][i], 0, 0, 0);
    }

    // ---- pass A: mask+scale, float4 logit store, int4 label load, track maxes ----
    unsigned long long ybits = 0ull;
    float mxn = -3.0e38f, mxp = -3.0e38f;
    int cnt = 0;
    #pragma unroll
    for (int j = 0; j < 4; ++j) {
        const int n0 = bn + wn + j*16 + (lane >> 4) * 4;
        const intx4 p4 = *(const intx4*)&amask[b * SEQ + n0];
        #pragma unroll
        for (int i = 0; i < 4; ++i) {
            const int m = bm + wm + i*16 + lr;
            const size_t lidx = ((size_t)bh * SEQ + m) * SEQ + n0;
            const intx4 y4 = *(const intx4*)&labels[lidx];
            floatx4 vout;
            #pragma unroll
            for (int rg = 0; rg < 4; ++rg) {
                const int n = n0 + rg;
                const float padn = (float)p4[rg];
                float v = acc[j][i][rg];
                v = v * padn - (1.0f - padn) * BIGF;   // pad mask (ref order)
                if (m > n) v -= BIGF;                  // tril(-1) causal mask
                v *= 0.125f;                           // / sqrt(64)
                vout[rg] = v;
                const int y = y4[rg] & 1;
                ybits |= ((unsigned long long)y) << cnt;
                float vn = y ? (-v - BIGF) : v;        // (1-2y)*v - y*BIG
                float vp = y ? (-v)        : (v - BIGF);
                mxn = fmaxf(mxn, vn);
                mxp = fmaxf(mxp, vp);
                acc[j][i][rg] = v;                     // keep masked value for pass B
                ++cnt;
            }
            *(floatx4*)&logits[lidx] = vout;
        }
    }

    // ---- pass B: sums of exp(v - max), independent expfs ----
    float smn = 0.f, smp = 0.f;
    cnt = 0;
    #pragma unroll
    for (int j = 0; j < 4; ++j) {
        #pragma unroll
        for (int i = 0; i < 4; ++i) {
            #pragma unroll
            for (int rg = 0; rg < 4; ++rg) {
                const float v = acc[j][i][rg];
                const int y = (int)((ybits >> cnt) & 1ull);
                float vn = y ? (-v - BIGF) : v;
                float vp = y ? (-v)        : (v - BIGF);
                smn += __expf(vn - mxn);
                smp += __expf(vp - mxp);
                ++cnt;
            }
        }
    }

    // ---- wave reduce (64 lanes) ----
    #pragma unroll
    for (int off = 32; off > 0; off >>= 1) {
        float mo = __shfl_down(mxn, off), so = __shfl_down(smn, off);
        lse_merge(mxn, smn, mo, so);
        mo = __shfl_down(mxp, off); so = __shfl_down(smp, off);
        lse_merge(mxp, smp, mo, so);
    }
    if (lane == 0) { smx[0][wave] = mxn; ssm[0][wave] = smn; smx[1][wave] = mxp; ssm[1][wave] = smp; }
    __syncthreads();
    if (tid == 0) {
        float mn = smx[0][0], sn = ssm[0][0], mp = smx[1][0], sp = ssm[1][0];
        #pragma unroll
        for (int u = 1; u < 4; ++u) {
            lse_merge(mn, sn, smx[0][u], ssm[0][u]);
            lse_merge(mp, sp, smx[1][u], ssm[1][u]);
        }
        const int chunk = blockIdx.x * 4 + blockIdx.y;      // 0..15
        float4 res = {mn, sn, mp, sp};
        *(float4*)&partials[(size_t)(bh * NCHUNK + chunk) * 4] = res;
    }
}

static __device__ __forceinline__ float lae0(float x) {   // logaddexp(0, x)
    return fmaxf(x, 0.f) + log1pf(__expf(-fabsf(x)));
}

__global__ __launch_bounds__(256) void ce_final_kernel(
    const float* __restrict__ partials, float* __restrict__ out)
{
    __shared__ float red[256];
    const int t = threadIdx.x;
    float val = 0.f;
    if (t < BATCH * ENTS) {
        float mn = -3.0e38f, sn = 0.f, mp = -3.0e38f, sp = 0.f;
        for (int c = 0; c < NCHUNK; ++c) {
            const float* p = &partials[(size_t)(t * NCHUNK + c) * 4];
            lse_merge(mn, sn, p[0], p[1]);
            lse_merge(mp, sp, p[2], p[3]);
        }
        float lsen = mn + logf(sn);
        float lsep = mp + logf(sp);
        val = lae0(lsen) + lae0(lsep);
    }
    red[t] = val;
    __syncthreads();
    for (int s2 = 128; s2 > 0; s2 >>= 1) {
        if (t < s2) red[t] += red[t + s2];
        __syncthreads();
    }
    if (t == 0) out[0] = red[0] / (float)(BATCH * ENTS);
}

extern "C" void kernel_launch(void* const* d_in, const int* in_sizes, int n_in,
                              void* d_out, int out_size, void* d_ws, size_t ws_size,
                              hipStream_t stream) {
    const float* X      = (const float*)d_in[0];   // (16,512,768)
    const int*   amask  = (const int*)d_in[1];     // (16,512)
    const int*   labels = (const int*)d_in[2];     // (16,9,512,512)
    const float* W      = (const float*)d_in[3];   // (768,1152)
    const float* bias   = (const float*)d_in[4];   // (1152,)

    float* out    = (float*)d_out;
    float* logits = out + 1;                       // temp_logits (16,9,512,512)

    float* sin_t = (float*)d_ws;                         // 16384 f32
    float* cos_t = sin_t + SEQ * 32;                     // 16384 f32
    ushort_t* Xb   = (ushort_t*)(cos_t + SEQ * 32);      // 6291456 bf16
    ushort_t* Wt   = Xb + (size_t)BATCH * SEQ * HID;     // 884736 bf16  [n][k]
    ushort_t* qbuf = Wt + (size_t)NOUT * HID;            // 16*9*512*64 bf16
    ushort_t* kbuf = qbuf + (size_t)BATCH * ENTS * SEQ * DD;
    float* partials = (float*)(kbuf + (size_t)BATCH * ENTS * SEQ * DD); // 144*16*4 f32

    rope_table_kernel<<<64, 256, 0, stream>>>(sin_t, cos_t);
    cvt_x_kernel<<<1024, 256, 0, stream>>>(X, Xb, BATCH * SEQ * HID);
    cvt_w_kernel<<<(NOUT * HID + 255) / 256, 256, 0, stream>>>(W, Wt);
    proj_rope_kernel<<<dim3(64, 9), 256, 0, stream>>>(Xb, Wt, bias, sin_t, cos_t, qbuf, kbuf);
    qk_mask_ce_kernel<<<dim3(4, 4, 144), 256, 0, stream>>>(qbuf, kbuf, amask, labels, logits, partials);
    ce_final_kernel<<<1, 256, 0, stream>>>(partials, out);
}